// Round 1
// 411.523 us; speedup vs baseline: 1.0548x; 1.0548x over previous
//
#include <hip/hip_runtime.h>
#include <stdint.h>

#define QMAXF 127.0f

constexpr int Mdim = 8192;
constexpr int Kdim = 4096;
constexpr int Ndim = 4096;
constexpr int PREP_BLOCKS = 2048;

using i32x4 = __attribute__((ext_vector_type(4))) int;

__device__ __forceinline__ void async_copy16(const void* g, void* l) {
    __builtin_amdgcn_global_load_lds(
        (const __attribute__((address_space(1))) void*)g,
        (__attribute__((address_space(3))) void*)l,
        16, 0, 0);
}

// ---------------------------------------------------------------------------
// Pass 1: per-block |x| maxima (plain stores, NO atomics) + w int32->int8.
// ---------------------------------------------------------------------------
__global__ void prep_kernel(const float* __restrict__ x,
                            const int* __restrict__ w32,
                            float* __restrict__ blockmax,
                            int8_t* __restrict__ w8) {
    float m = 0.f;
    const float4* x4 = (const float4*)x;
    const int n4x = Mdim * Kdim / 4;
    for (int i = blockIdx.x * blockDim.x + threadIdx.x; i < n4x;
         i += gridDim.x * blockDim.x) {
        float4 v = x4[i];
        m = fmaxf(fmaxf(fabsf(v.x), fabsf(v.y)),
                  fmaxf(m, fmaxf(fabsf(v.z), fabsf(v.w))));
    }
#pragma unroll
    for (int off = 32; off > 0; off >>= 1)
        m = fmaxf(m, __shfl_down(m, off, 64));
    __shared__ float red[4];
    if ((threadIdx.x & 63) == 0) red[threadIdx.x >> 6] = m;
    __syncthreads();
    if (threadIdx.x == 0)
        blockmax[blockIdx.x] =
            fmaxf(fmaxf(red[0], red[1]), fmaxf(red[2], red[3]));

    // fused: narrow w (independent of the reduction above)
    const int4* in4 = (const int4*)w32;
    char4* out4 = (char4*)w8;
    const int n4w = Ndim * Kdim / 4;
    for (int i = blockIdx.x * blockDim.x + threadIdx.x; i < n4w;
         i += gridDim.x * blockDim.x) {
        int4 v = in4[i];
        char4 c;
        c.x = (signed char)v.x;
        c.y = (signed char)v.y;
        c.z = (signed char)v.z;
        c.w = (signed char)v.w;
        out4[i] = c;
    }
}

// Pass 2: reduce 2048 block maxima -> s_x = max/127 (one block, ~3 us)
__global__ void finalize_kernel(const float* __restrict__ blockmax,
                                float* __restrict__ sx) {
    float m = 0.f;
    for (int i = threadIdx.x; i < PREP_BLOCKS; i += 256)
        m = fmaxf(m, blockmax[i]);
#pragma unroll
    for (int off = 32; off > 0; off >>= 1)
        m = fmaxf(m, __shfl_down(m, off, 64));
    __shared__ float red[4];
    if ((threadIdx.x & 63) == 0) red[threadIdx.x >> 6] = m;
    __syncthreads();
    if (threadIdx.x == 0)
        *sx = fmaxf(fmaxf(red[0], red[1]), fmaxf(red[2], red[3])) / QMAXF;
}

// Pass 3: quantize x -> int8 with the (now known) scalar scale
__global__ void quant_x_kernel(const float* __restrict__ x,
                               const float* __restrict__ sxp,
                               int8_t* __restrict__ xq, int n4) {
    const float s = *sxp;
    const float4* x4 = (const float4*)x;
    char4* q4 = (char4*)xq;
    for (int i = blockIdx.x * blockDim.x + threadIdx.x; i < n4;
         i += gridDim.x * blockDim.x) {
        float4 v = x4[i];
        char4 q;
        q.x = (signed char)(int)fminf(QMAXF, fmaxf(-QMAXF, rintf(v.x / s)));
        q.y = (signed char)(int)fminf(QMAXF, fmaxf(-QMAXF, rintf(v.y / s)));
        q.z = (signed char)(int)fminf(QMAXF, fmaxf(-QMAXF, rintf(v.z / s)));
        q.w = (signed char)(int)fminf(QMAXF, fmaxf(-QMAXF, rintf(v.w / s)));
        q4[i] = q;
    }
}

// ---------------------------------------------------------------------------
// int8 GEMM: C[M,N] = Xq[M,K] . Wq[N,K]^T
// 256x256 tile, BK=128 bytes, 8 waves (2Mx4N per 128x128 quadrant), 8-phase
// schedule (T3+T4): per phase {ds_read subtile | stage 1 half-tile | raw
// s_barrier | lgkmcnt(0) | setprio(1) 16x MFMA setprio(0) | raw s_barrier}.
// Counted vmcnt(6) once per K-tile keeps 3 half-tiles (6 loads) in flight
// across barriers. LDS 128 KiB = 2 buffers x (A 32K + B 32K), XOR-chunk
// swizzle (slot = chunk ^ (row&7)) applied at the pre-swizzled global source
// (global_load_lds writes linearly) and on the ds_read address -> 0 bank
// conflicts (unchanged from previous version, verified).
//
// Ledger (group computing K-tile T, buffer T&1):
//   P1: read A0+B0(T), stage B0(T+1)   [other buffer; B0(T-1) last read prev P4]
//   P2: read B1(T),    stage A0(T+2)   [same buffer; A0(T) last read P1]
//   P3: read A1(T),    stage B1(T+2)   [B1(T) last read P2]
//   P4: read B0(T),    stage A1(T+2)   [A1(T) last read P3], vmcnt(6)
//   vmcnt(6) leaves newest 3 pairs (= tile T+2 stages) outstanding ->
//   tile T+1 fully landed before the next group's reads. Tail: vmcnt(0).
// ---------------------------------------------------------------------------
#define BM 256
#define BN 256
#define BKB 128
#define NKT (Kdim / BKB)  // 32

#define BAR() __builtin_amdgcn_s_barrier()
#define LGKM0()                                           \
    do {                                                  \
        asm volatile("s_waitcnt lgkmcnt(0)" ::: "memory");\
        __builtin_amdgcn_sched_barrier(0);                \
    } while (0)

__global__ __launch_bounds__(512, 2) void gemm_i8_kernel(
    const int8_t* __restrict__ Xq, const int8_t* __restrict__ Wq,
    const float* __restrict__ sxp, const float* __restrict__ s_w,
    const float* __restrict__ bias, float* __restrict__ Y) {
    __shared__ int8_t lds[131072];  // [buf][A 32K | B 32K]

    const int t = threadIdx.x;
    const int w = t >> 6;
    const int l = t & 63;
    const int lane15 = l & 15;
    const int lquad = l >> 4;
    const int swz7 = l & 7;

    // XCD-aware bijective swizzle: 512 blocks, 8 XCDs, 64 contiguous per XCD
    const int flat = blockIdx.y * gridDim.x + blockIdx.x;
    const int swzb = (flat & 7) * 64 + (flat >> 3);
    const int bn = (swzb & 15) * BN;
    const int bm = (swzb >> 4) * BM;

    // --- staging source (per-thread, pre-swizzled global address) ---------
    // half-tile = 128 rows x 128 B = 16 KB = 1024 chunks of 16 B.
    // thread t owns chunks t (s=0) and t+512 (s=1): row r = t>>3 (+64 for
    // s=1), slot p = t&7; data placed there is global chunk p ^ (r&7).
    const int r0 = t >> 3;
    const int cOff = ((t & 7) ^ (r0 & 7)) * 16;
    const int8_t* aS = Xq + (size_t)(bm + r0) * Kdim + cOff;
    const int8_t* bS = Wq + (size_t)(bn + r0) * Kdim + cOff;
    const int wb = w * 1024;  // wave-uniform LDS offset (HW adds lane*16)

    // --- fragment-read bases (8 waves tile each 128x128 quadrant 2Mx4N) ---
    const int aRdBase = ((w >> 2) * 64 + lane15) * BKB;
    const int bRdBase = ((w & 3) * 32 + lane15) * BKB;
    const int kOff0 = (lquad ^ swz7) * 16;
    const int kOff1 = kOff0 ^ 64;

    i32x4 acc[2][2][4][2] = {};
    i32x4 a[4][2], b[2][2];

    int8_t* const ldsA_ = lds;
    int8_t* const ldsB_ = lds + 32768;

#define STAGE(SRC, LBASE, h, kt)                                              \
    do {                                                                      \
        if ((kt) < NKT) {                                                     \
            const int8_t* _s =                                                \
                (SRC) + (size_t)(h) * 128 * Kdim + (size_t)(kt) * BKB;        \
            int8_t* _d = (LBASE) + ((kt) & 1) * 65536 + (h) * 16384 + wb;     \
            async_copy16(_s, _d);                                             \
            async_copy16(_s + (size_t)64 * Kdim, _d + 8192);                  \
        }                                                                     \
    } while (0)

#define LDA(mh)                                                               \
    {                                                                         \
        _Pragma("unroll") for (int i = 0; i < 4; ++i) {                       \
            a[i][0] = *(const i32x4*)(curA + aRdBase + (mh) * 16384 +         \
                                      i * 2048 + kOff0);                      \
            a[i][1] = *(const i32x4*)(curA + aRdBase + (mh) * 16384 +         \
                                      i * 2048 + kOff1);                      \
        }                                                                     \
    }

#define LDB(nh)                                                               \
    {                                                                         \
        _Pragma("unroll") for (int j = 0; j < 2; ++j) {                       \
            b[j][0] = *(const i32x4*)(curB + bRdBase + (nh) * 16384 +         \
                                      j * 2048 + kOff0);                      \
            b[j][1] = *(const i32x4*)(curB + bRdBase + (nh) * 16384 +         \
                                      j * 2048 + kOff1);                      \
        }                                                                     \
    }

#define MFMA_Q(mh, nh)                                                        \
    do {                                                                      \
        __builtin_amdgcn_s_setprio(1);                                        \
        _Pragma("unroll") for (int i = 0; i < 4; ++i)                         \
            _Pragma("unroll") for (int j = 0; j < 2; ++j) {                   \
            acc[mh][nh][i][j] = __builtin_amdgcn_mfma_i32_16x16x64_i8(        \
                a[i][0], b[j][0], acc[mh][nh][i][j], 0, 0, 0);                \
            acc[mh][nh][i][j] = __builtin_amdgcn_mfma_i32_16x16x64_i8(        \
                a[i][1], b[j][1], acc[mh][nh][i][j], 0, 0, 0);                \
        }                                                                     \
        __builtin_amdgcn_s_setprio(0);                                        \
    } while (0)

#define GROUP(T, BOFF)                                                        \
    do {                                                                      \
        const int8_t* curA = ldsA_ + (BOFF);                                  \
        const int8_t* curB = ldsB_ + (BOFF);                                  \
        /* P1 */                                                              \
        LDA(0); LDB(0);                                                       \
        STAGE(bS, ldsB_, 0, (T) + 1);                                         \
        asm volatile("s_waitcnt lgkmcnt(8)" ::: "memory");                    \
        BAR(); LGKM0(); MFMA_Q(0, 0); BAR();                                  \
        /* P2 */                                                              \
        LDB(1);                                                               \
        STAGE(aS, ldsA_, 0, (T) + 2);                                         \
        BAR(); LGKM0(); MFMA_Q(0, 1); BAR();                                  \
        /* P3 */                                                              \
        LDA(1);                                                               \
        STAGE(bS, ldsB_, 1, (T) + 2);                                         \
        BAR(); LGKM0(); MFMA_Q(1, 1); BAR();                                  \
        /* P4 */                                                              \
        LDB(0);                                                               \
        STAGE(aS, ldsA_, 1, (T) + 2);                                         \
        if ((T) + 2 < NKT) {                                                  \
            asm volatile("s_waitcnt vmcnt(6)" ::: "memory");                  \
        } else {                                                              \
            asm volatile("s_waitcnt vmcnt(0)" ::: "memory");                  \
        }                                                                     \
        BAR(); LGKM0(); MFMA_Q(1, 0); BAR();                                  \
    } while (0)

    // prologue: tile0 fully + tile1 {A0,B1,A1}; vmcnt(6) leaves exactly the
    // 3 tile-1 half-tiles (6 loads) in flight = steady-state invariant.
    STAGE(aS, ldsA_, 0, 0);
    STAGE(bS, ldsB_, 1, 0);
    STAGE(aS, ldsA_, 1, 0);
    STAGE(bS, ldsB_, 0, 0);
    STAGE(aS, ldsA_, 0, 1);
    STAGE(bS, ldsB_, 1, 1);
    STAGE(aS, ldsA_, 1, 1);
    asm volatile("s_waitcnt vmcnt(6)" ::: "memory");
    BAR();

    for (int t2 = 0; t2 < NKT; t2 += 2) {
        GROUP(t2, 0);          // compute K-tile t2   (buffer 0)
        GROUP(t2 + 1, 65536);  // compute K-tile t2+1 (buffer 1)
    }

    // epilogue: C/D layout col=lane&15, row=(lane>>4)*4+reg (16x16 shapes)
    const float sx = *sxp;
    const int wmE = (w >> 2) * 64;
    const int wnE = (w & 3) * 32;
#pragma unroll
    for (int nh = 0; nh < 2; ++nh) {
#pragma unroll
        for (int j = 0; j < 2; ++j) {
            const int col = bn + nh * 128 + wnE + j * 16 + lane15;
            const float sc = sx * s_w[col];
            const float bs = bias[col];
#pragma unroll
            for (int mh = 0; mh < 2; ++mh) {
#pragma unroll
                for (int i = 0; i < 4; ++i) {
                    const int row = bm + mh * 128 + wmE + i * 16 + lquad * 4;
                    float* yp = Y + (size_t)row * Ndim + col;
#pragma unroll
                    for (int r = 0; r < 4; ++r)
                        yp[(size_t)r * Ndim] =
                            (float)acc[mh][nh][i][j][r] * sc + bs;
                }
            }
        }
    }
}

extern "C" void kernel_launch(void* const* d_in, const int* in_sizes, int n_in,
                              void* d_out, int out_size, void* d_ws,
                              size_t ws_size, hipStream_t stream) {
    const float* x = (const float*)d_in[0];
    const int* w_q = (const int*)d_in[1];  // integer inputs arrive as int32
    const float* s_w = (const float*)d_in[2];
    const float* bias = (const float*)d_in[3];
    float* y = (float*)d_out;

    float* sx = (float*)d_ws;                       // [0]      scalar scale
    float* blockmax = (float*)((char*)d_ws + 256);  // [256]    2048 floats
    int8_t* xq = (int8_t*)d_ws + 16384;
    int8_t* wq8 = (int8_t*)d_ws + 16384 + (size_t)Mdim * Kdim;

    prep_kernel<<<PREP_BLOCKS, 256, 0, stream>>>(x, w_q, blockmax, wq8);
    finalize_kernel<<<1, 256, 0, stream>>>(blockmax, sx);
    quant_x_kernel<<<PREP_BLOCKS, 256, 0, stream>>>(x, sx, xq,
                                                    Mdim * Kdim / 4);

    dim3 grid(Ndim / BN, Mdim / BM);
    gemm_i8_kernel<<<grid, 512, 0, stream>>>(xq, wq8, sx, s_w, bias, y);
}

// Round 2
// 404.509 us; speedup vs baseline: 1.0731x; 1.0173x over previous
//
#include <hip/hip_runtime.h>
#include <stdint.h>

#define QMAXF 127.0f

constexpr int Mdim = 8192;
constexpr int Kdim = 4096;
constexpr int Ndim = 4096;
constexpr int PREP_BLOCKS = 2048;

using i32x4 = __attribute__((ext_vector_type(4))) int;

__device__ __forceinline__ void async_copy16(const void* g, void* l) {
    __builtin_amdgcn_global_load_lds(
        (const __attribute__((address_space(1))) void*)g,
        (__attribute__((address_space(3))) void*)l,
        16, 0, 0);
}

// ---------------------------------------------------------------------------
// Pass 1: per-block |x| maxima (plain stores, NO atomics) + w int32->int8.
// ---------------------------------------------------------------------------
__global__ void prep_kernel(const float* __restrict__ x,
                            const int* __restrict__ w32,
                            float* __restrict__ blockmax,
                            int8_t* __restrict__ w8) {
    float m = 0.f;
    const float4* x4 = (const float4*)x;
    const int n4x = Mdim * Kdim / 4;
    for (int i = blockIdx.x * blockDim.x + threadIdx.x; i < n4x;
         i += gridDim.x * blockDim.x) {
        float4 v = x4[i];
        m = fmaxf(fmaxf(fabsf(v.x), fabsf(v.y)),
                  fmaxf(m, fmaxf(fabsf(v.z), fabsf(v.w))));
    }
#pragma unroll
    for (int off = 32; off > 0; off >>= 1)
        m = fmaxf(m, __shfl_down(m, off, 64));
    __shared__ float red[4];
    if ((threadIdx.x & 63) == 0) red[threadIdx.x >> 6] = m;
    __syncthreads();
    if (threadIdx.x == 0)
        blockmax[blockIdx.x] =
            fmaxf(fmaxf(red[0], red[1]), fmaxf(red[2], red[3]));

    // fused: narrow w (independent of the reduction above)
    const int4* in4 = (const int4*)w32;
    char4* out4 = (char4*)w8;
    const int n4w = Ndim * Kdim / 4;
    for (int i = blockIdx.x * blockDim.x + threadIdx.x; i < n4w;
         i += gridDim.x * blockDim.x) {
        int4 v = in4[i];
        char4 c;
        c.x = (signed char)v.x;
        c.y = (signed char)v.y;
        c.z = (signed char)v.z;
        c.w = (signed char)v.w;
        out4[i] = c;
    }
}

// Pass 2: reduce 2048 block maxima -> s_x = max/127 (one block, ~3 us)
__global__ void finalize_kernel(const float* __restrict__ blockmax,
                                float* __restrict__ sx) {
    float m = 0.f;
    for (int i = threadIdx.x; i < PREP_BLOCKS; i += 256)
        m = fmaxf(m, blockmax[i]);
#pragma unroll
    for (int off = 32; off > 0; off >>= 1)
        m = fmaxf(m, __shfl_down(m, off, 64));
    __shared__ float red[4];
    if ((threadIdx.x & 63) == 0) red[threadIdx.x >> 6] = m;
    __syncthreads();
    if (threadIdx.x == 0)
        *sx = fmaxf(fmaxf(red[0], red[1]), fmaxf(red[2], red[3])) / QMAXF;
}

// Pass 3: quantize x -> int8 with the (now known) scalar scale
__global__ void quant_x_kernel(const float* __restrict__ x,
                               const float* __restrict__ sxp,
                               int8_t* __restrict__ xq, int n4) {
    const float s = *sxp;
    const float4* x4 = (const float4*)x;
    char4* q4 = (char4*)xq;
    for (int i = blockIdx.x * blockDim.x + threadIdx.x; i < n4;
         i += gridDim.x * blockDim.x) {
        float4 v = x4[i];
        char4 q;
        q.x = (signed char)(int)fminf(QMAXF, fmaxf(-QMAXF, rintf(v.x / s)));
        q.y = (signed char)(int)fminf(QMAXF, fmaxf(-QMAXF, rintf(v.y / s)));
        q.z = (signed char)(int)fminf(QMAXF, fmaxf(-QMAXF, rintf(v.z / s)));
        q.w = (signed char)(int)fminf(QMAXF, fmaxf(-QMAXF, rintf(v.w / s)));
        q4[i] = q;
    }
}

// ---------------------------------------------------------------------------
// int8 GEMM: C[M,N] = Xq[M,K] . Wq[N,K]^T
// 256x256 tile, BK=128 bytes, 8 waves (2Mx4N), read-ahead pipelined schedule.
//
// R1 post-mortem: two-barrier phases put ds_read and MFMA in disjoint regions
// -> LDS time (224 b128 x 4cy = 896cy/tile/CU) and MFMA time (653cy/SIMD)
// ADD: 653/(896+653) = 42% = measured MfmaUtil. Fix: issue phase p+1's
// fragment reads BEFORE phase p's MFMA cluster, wait with COUNTED lgkmcnt on
// the previous phase's reads only -> LDS pipe overlaps matrix pipe.
//
// Per-tile schedule (tile T, buf b=T&1, other b'; quadrants Q00->Q01->Q11->Q10;
// b0 persists in regs the whole tile -> 24 ds_reads/tile, no B0 re-read):
//   P1: read b1(T)[4];  lgkm(4) [drains a0(T)+b0(T)]; MFMA Q00(a0,b0);
//       stage B1(T+1)->b'; vmcnt(6); BAR
//   P2: read a1(T)[8];  lgkm(8) [drains b1(T)];       MFMA Q01(a0,b1);
//       stage A1(T+1)->b'; vmcnt(6); BAR
//   P3: read a0(T+1)[8] from b'; lgkm(8) [drains a1]; MFMA Q11(a1,b1);
//       stage A0(T+2)->b;  vmcnt(6); BAR
//   P4: MFMA Q10(a1,b0) [no wait: operands long drained];
//       read b0(T+1)[4] from b' (after MFMA: reg WAR); stage B0(T+2)->b;
//       vmcnt(6); BAR
//
// Safety proofs (steady state):
//  * stage->read: every half-tile staged 3+ phases before its read; uniform
//    vmcnt(6) leaves exactly the 3 newest stage-pairs in flight, so the pair
//    with "deadline = this phase end" is always complete; BAR makes it
//    cross-wave. (e.g. A0(T+1) staged P3(T-1): at end P2(T) queue =
//    [A0(T+1),B0(T+1),B1(T+1),A1(T+1)], vmcnt(6) drains A0(T+1) -> read
//    @P3(T) safe.)
//  * read->stage (WAR): stage A0(T+2)@P3(T) overwrites LDS A0(T), whose only
//    reads were issued @P3(T-1) and drained by every wave's lgkm before its
//    MFMA Q00(T); barriers since -> safe. Same shape for B1/A1/B0.
//  * Tail: stages with kt>=NKT clamp to kt-2 (same parity -> same buffer;
//    region data dead, rewrite harmless, keeps vmcnt(6) queue depth uniform,
//    keeps addresses in-bounds). Last tile's P3/P4 read-aheads load garbage
//    into regs that are never consumed.
// Registers: frags 96 (a0/a1 32 ea, b0/b1 16 ea, all single-set: each reload
// provably follows last use) + acc 128 (AGPR) + misc ~25 <= 256 -> 2 w/SIMD.
// ---------------------------------------------------------------------------
#define BM 256
#define BN 256
#define BKB 128
#define NKT (Kdim / BKB)  // 32

#define BARF()                              \
    do {                                    \
        __builtin_amdgcn_s_barrier();       \
        __builtin_amdgcn_sched_barrier(0);  \
    } while (0)

#define WAITLGKM(N)                                                  \
    do {                                                             \
        asm volatile("s_waitcnt lgkmcnt(" #N ")" ::: "memory");      \
        __builtin_amdgcn_sched_barrier(0);                           \
    } while (0)

#define WAITVM(N) asm volatile("s_waitcnt vmcnt(" #N ")" ::: "memory")

__global__ __launch_bounds__(512, 2) void gemm_i8_kernel(
    const int8_t* __restrict__ Xq, const int8_t* __restrict__ Wq,
    const float* __restrict__ sxp, const float* __restrict__ s_w,
    const float* __restrict__ bias, float* __restrict__ Y) {
    __shared__ int8_t lds[131072];  // [buf][A 32K | B 32K]

    const int t = threadIdx.x;
    const int w = t >> 6;
    const int l = t & 63;
    const int lane15 = l & 15;
    const int lquad = l >> 4;
    const int swz7 = lane15 & 7;

    // XCD-aware bijective swizzle: 512 blocks, 8 XCDs, 64 contiguous per XCD
    const int flat = blockIdx.y * gridDim.x + blockIdx.x;
    const int swzb = (flat & 7) * 64 + (flat >> 3);
    const int bn = (swzb & 15) * BN;
    const int bm = (swzb >> 4) * BM;

    // --- staging source (per-thread, pre-swizzled global address) ---------
    // half-tile = 128 rows x 128 B = 1024 chunks of 16 B; thread t owns rows
    // r0 = t>>3 and r0+64, slot p = t&7 holding global chunk p ^ (r&7).
    const int r0 = t >> 3;
    const int cOff = ((t & 7) ^ (r0 & 7)) * 16;
    const int8_t* aS = Xq + (size_t)(bm + r0) * Kdim + cOff;
    const int8_t* bS = Wq + (size_t)(bn + r0) * Kdim + cOff;
    const int wb = w * 1024;  // wave-uniform LDS offset (HW adds lane*16)

    // --- fragment-read bases (8 waves tile the 256x256 output 2Mx4N) ------
    const int aRdBase = ((w >> 2) * 64 + lane15) * BKB;
    const int bRdBase = ((w & 3) * 32 + lane15) * BKB;
    const int kOff0 = (lquad ^ swz7) * 16;
    const int kOff1 = kOff0 ^ 64;

    i32x4 acc[2][2][4][2] = {};
    i32x4 a0[4][2], a1[4][2], b0[2][2], b1[2][2];

    int8_t* const ldsA_ = lds;
    int8_t* const ldsB_ = lds + 32768;

#define STAGE(SRC, LBASE, h, kt)                                              \
    do {                                                                      \
        const int _kt = (kt) < NKT ? (kt) : (NKT - 2 + ((kt) & 1));           \
        const int8_t* _s =                                                    \
            (SRC) + (size_t)(h) * 128 * Kdim + (size_t)_kt * BKB;             \
        int8_t* _d = (LBASE) + (_kt & 1) * 65536 + (h) * 16384 + wb;          \
        async_copy16(_s, _d);                                                 \
        async_copy16(_s + (size_t)64 * Kdim, _d + 8192);                      \
    } while (0)

#define LDFRAG_A(dst, BOFF, mh)                                               \
    do {                                                                      \
        const int8_t* _p = lds + (BOFF) + aRdBase + (mh) * 16384;             \
        _Pragma("unroll") for (int i = 0; i < 4; ++i) {                       \
            dst[i][0] = *(const i32x4*)(_p + i * 2048 + kOff0);               \
            dst[i][1] = *(const i32x4*)(_p + i * 2048 + kOff1);               \
        }                                                                     \
    } while (0)

#define LDFRAG_B(dst, BOFF, nh)                                               \
    do {                                                                      \
        const int8_t* _p = lds + 32768 + (BOFF) + bRdBase + (nh) * 16384;     \
        _Pragma("unroll") for (int j = 0; j < 2; ++j) {                       \
            dst[j][0] = *(const i32x4*)(_p + j * 2048 + kOff0);               \
            dst[j][1] = *(const i32x4*)(_p + j * 2048 + kOff1);               \
        }                                                                     \
    } while (0)

#define MFMAQ(mh, nh, A, B)                                                   \
    do {                                                                      \
        __builtin_amdgcn_s_setprio(1);                                        \
        _Pragma("unroll") for (int i = 0; i < 4; ++i)                         \
            _Pragma("unroll") for (int j = 0; j < 2; ++j) {                   \
                acc[mh][nh][i][j] = __builtin_amdgcn_mfma_i32_16x16x64_i8(    \
                    (A)[i][0], (B)[j][0], acc[mh][nh][i][j], 0, 0, 0);        \
                acc[mh][nh][i][j] = __builtin_amdgcn_mfma_i32_16x16x64_i8(    \
                    (A)[i][1], (B)[j][1], acc[mh][nh][i][j], 0, 0, 0);        \
            }                                                                 \
        __builtin_amdgcn_s_setprio(0);                                        \
    } while (0)

#define GROUP(T, BOFF, OBOFF)                                                 \
    do {                                                                      \
        /* P1: Q00 */                                                         \
        LDFRAG_B(b1, BOFF, 1);                                                \
        WAITLGKM(4);                                                          \
        MFMAQ(0, 0, a0, b0);                                                  \
        STAGE(bS, ldsB_, 1, (T) + 1);                                         \
        WAITVM(6);                                                            \
        BARF();                                                               \
        /* P2: Q01 */                                                         \
        LDFRAG_A(a1, BOFF, 1);                                                \
        WAITLGKM(8);                                                          \
        MFMAQ(0, 1, a0, b1);                                                  \
        STAGE(aS, ldsA_, 1, (T) + 1);                                         \
        WAITVM(6);                                                            \
        BARF();                                                               \
        /* P3: Q11 */                                                         \
        LDFRAG_A(a0, OBOFF, 0);                                               \
        WAITLGKM(8);                                                          \
        MFMAQ(1, 1, a1, b1);                                                  \
        STAGE(aS, ldsA_, 0, (T) + 2);                                         \
        WAITVM(6);                                                            \
        BARF();                                                               \
        /* P4: Q10 */                                                         \
        MFMAQ(1, 0, a1, b0);                                                  \
        LDFRAG_B(b0, OBOFF, 0);                                               \
        STAGE(bS, ldsB_, 0, (T) + 2);                                         \
        WAITVM(6);                                                            \
        BARF();                                                               \
    } while (0)

    // prologue: tile0 {A0,B0,B1} must land; {A1(0),A0(1),B0(1)} may fly (=3
    // pairs, the steady vmcnt(6) invariant). Then prefetch a0/b0 frags.
    STAGE(aS, ldsA_, 0, 0);
    STAGE(bS, ldsB_, 0, 0);
    STAGE(bS, ldsB_, 1, 0);
    STAGE(aS, ldsA_, 1, 0);
    STAGE(aS, ldsA_, 0, 1);
    STAGE(bS, ldsB_, 0, 1);
    WAITVM(6);
    BARF();
    LDFRAG_A(a0, 0, 0);
    LDFRAG_B(b0, 0, 0);

    for (int t2 = 0; t2 < NKT; t2 += 2) {
        GROUP(t2, 0, 65536);
        GROUP(t2 + 1, 65536, 0);
    }

    // epilogue: C/D layout col=lane&15, row=(lane>>4)*4+reg (16x16 shapes)
    const float sx = *sxp;
    const int wmE = (w >> 2) * 64;
    const int wnE = (w & 3) * 32;
#pragma unroll
    for (int nh = 0; nh < 2; ++nh) {
#pragma unroll
        for (int j = 0; j < 2; ++j) {
            const int col = bn + nh * 128 + wnE + j * 16 + lane15;
            const float sc = sx * s_w[col];
            const float bs = bias[col];
#pragma unroll
            for (int mh = 0; mh < 2; ++mh) {
#pragma unroll
                for (int i = 0; i < 4; ++i) {
                    const int row = bm + mh * 128 + wmE + i * 16 + lquad * 4;
                    float* yp = Y + (size_t)row * Ndim + col;
#pragma unroll
                    for (int r = 0; r < 4; ++r)
                        yp[(size_t)r * Ndim] =
                            (float)acc[mh][nh][i][j][r] * sc + bs;
                }
            }
        }
    }
}

extern "C" void kernel_launch(void* const* d_in, const int* in_sizes, int n_in,
                              void* d_out, int out_size, void* d_ws,
                              size_t ws_size, hipStream_t stream) {
    const float* x = (const float*)d_in[0];
    const int* w_q = (const int*)d_in[1];  // integer inputs arrive as int32
    const float* s_w = (const float*)d_in[2];
    const float* bias = (const float*)d_in[3];
    float* y = (float*)d_out;

    float* sx = (float*)d_ws;                       // [0]      scalar scale
    float* blockmax = (float*)((char*)d_ws + 256);  // [256]    2048 floats
    int8_t* xq = (int8_t*)d_ws + 16384;
    int8_t* wq8 = (int8_t*)d_ws + 16384 + (size_t)Mdim * Kdim;

    prep_kernel<<<PREP_BLOCKS, 256, 0, stream>>>(x, w_q, blockmax, wq8);
    finalize_kernel<<<1, 256, 0, stream>>>(blockmax, sx);
    quant_x_kernel<<<PREP_BLOCKS, 256, 0, stream>>>(x, sx, xq,
                                                    Mdim * Kdim / 4);

    dim3 grid(Ndim / BN, Mdim / BM);
    gemm_i8_kernel<<<grid, 512, 0, stream>>>(xq, wq8, sx, s_w, bias, y);
}